// Round 2
// baseline (319.069 us; speedup 1.0000x reference)
//
#include <hip/hip_runtime.h>
#include <hip/hip_bf16.h>

#define BB 64
#define WW 4096
#define HH 128

typedef unsigned short u16;
typedef unsigned int u32;

__device__ inline float bf2f(u16 u) {
    return __uint_as_float(((u32)u) << 16);
}
__device__ inline u16 f2bf(float f) {
    __hip_bfloat16 h = __float2bfloat16(f);
    return *reinterpret_cast<u16*>(&h);
}
__device__ inline void bf8_unpack(const uint4 r, float* o) {
    o[0] = __uint_as_float(r.x << 16);
    o[1] = __uint_as_float(r.x & 0xffff0000u);
    o[2] = __uint_as_float(r.y << 16);
    o[3] = __uint_as_float(r.y & 0xffff0000u);
    o[4] = __uint_as_float(r.z << 16);
    o[5] = __uint_as_float(r.z & 0xffff0000u);
    o[6] = __uint_as_float(r.w << 16);
    o[7] = __uint_as_float(r.w & 0xffff0000u);
}
__device__ inline float sigmoidf(float x) { return 1.0f / (1.0f + expf(-x)); }

// dtype-agnostic loaders --------------------------------------------------
template<bool FP32>
__device__ inline float ld1(const void* p, size_t i) {
    if (FP32) return ((const float*)p)[i];
    return bf2f(((const u16*)p)[i]);
}
// load 8 consecutive elements starting at element index g*8
template<bool FP32>
__device__ inline void ld8(const void* p, size_t g, float* o) {
    if (FP32) {
        float4 a = ((const float4*)p)[2 * g];
        float4 b = ((const float4*)p)[2 * g + 1];
        o[0] = a.x; o[1] = a.y; o[2] = a.z; o[3] = a.w;
        o[4] = b.x; o[5] = b.y; o[6] = b.z; o[7] = b.w;
    } else {
        uint4 r = ((const uint4*)p)[g];
        bf8_unpack(r, o);
    }
}
template<bool FP32>
__device__ inline void st1(void* p, size_t i, float v) {
    if (FP32) ((float*)p)[i] = v;
    else      ((u16*)p)[i] = f2bf(v);
}

// ---------------------------------------------------------------------------
// Sniff: decide whether global float tensors are bf16 or fp32.
// Reads 256 u32 words of encoder_output; if data is bf16, the LOW u16 of each
// word is a small bf16 (|v| <= 4 always). If data is fp32, the low u16 is
// uniform mantissa bits -> |bf16| <= 4 only ~50% of the time.
// flag[0] = 1.0 -> bf16 data; 0.0 -> fp32 data.
__global__ void sniff_kernel(const u32* __restrict__ encw, float* __restrict__ flag) {
    __shared__ int red[256];
    const int t = threadIdx.x;
    u32 w = encw[(size_t)t * 997];
    float v = bf2f((u16)(w & 0xffffu));
    red[t] = (fabsf(v) <= 4.0f) ? 1 : 0;   // NaN compares false -> 0
    __syncthreads();
    for (int s = 128; s > 0; s >>= 1) {
        if (t < s) red[t] += red[t + s];
        __syncthreads();
    }
    if (t == 0) flag[0] = (red[0] >= 240) ? 1.0f : 0.0f;
}

// ---------------------------------------------------------------------------
// K1: scores[b,w] = dot(enc[b,w,:], att_W[:H]) + (att_state[b].att_W[H:]) + att_b
template<bool FP32>
__global__ void scores_kernel(const void* __restrict__ enc,
                              const void* __restrict__ h0,
                              const void* __restrict__ c0,
                              const void* __restrict__ attW,
                              const void* __restrict__ attb,
                              const float* __restrict__ flag,
                              float* __restrict__ scores) {
    if ((flag[0] < 0.5f) != FP32) return;   // uniform early exit
    __shared__ float s_red[128];
    __shared__ float s_wa[128];
    __shared__ float s_bias;
    const int t = threadIdx.x;
    const int b = blockIdx.x >> 4;

    if (t < 128) {
        s_wa[t] = ld1<FP32>(attW, t);
        float hv = ld1<FP32>(h0, BB * HH + b * HH + t);
        float cv = ld1<FP32>(c0, BB * HH + b * HH + t);
        float ws = ld1<FP32>(attW, HH + t);
        s_red[t] = hv * cv * ws;
    }
    __syncthreads();
    for (int s = 64; s > 0; s >>= 1) {
        if (t < s) s_red[t] += s_red[t + s];
        __syncthreads();
    }
    if (t == 0) s_bias = s_red[0] + ld1<FP32>(attb, 0);
    __syncthreads();
    const float bias = s_bias;

    const int seg = t & 15;
    const int rg  = t >> 4;
    float wseg[8];
#pragma unroll
    for (int j = 0; j < 8; j++) wseg[j] = s_wa[seg * 8 + j];

    const size_t rowbase = (size_t)blockIdx.x * 256;
#pragma unroll 4
    for (int pass = 0; pass < 16; pass++) {
        const size_t row = rowbase + pass * 16 + rg;
        float v[8];
        ld8<FP32>(enc, row * 16 + seg, v);
        float d = 0.f;
#pragma unroll
        for (int j = 0; j < 8; j++) d += v[j] * wseg[j];
        d += __shfl_xor(d, 8, 16);
        d += __shfl_xor(d, 4, 16);
        d += __shfl_xor(d, 2, 16);
        d += __shfl_xor(d, 1, 16);
        if (seg == 0) scores[row] = d + bias;
    }
}

// ---------------------------------------------------------------------------
// K2: weight[b,j] = softmax_j([0, scores[b,0..W-2]])  (ws-only, dtype-free)
__global__ void softmax_kernel(const float* __restrict__ scores,
                               float* __restrict__ weight) {
    __shared__ float red[256];
    const int b = blockIdx.x;
    const int t = threadIdx.x;

    float lmax = -1e30f;
    for (int j = t; j < WW; j += 256) {
        float v = (j == 0) ? 0.f : scores[b * WW + j - 1];
        lmax = fmaxf(lmax, v);
    }
    red[t] = lmax;
    __syncthreads();
    for (int s = 128; s > 0; s >>= 1) {
        if (t < s) red[t] = fmaxf(red[t], red[t + s]);
        __syncthreads();
    }
    const float m = red[0];
    __syncthreads();

    float lsum = 0.f;
    for (int j = t; j < WW; j += 256) {
        float v = (j == 0) ? 0.f : scores[b * WW + j - 1];
        lsum += expf(v - m);
    }
    red[t] = lsum;
    __syncthreads();
    for (int s = 128; s > 0; s >>= 1) {
        if (t < s) red[t] += red[t + s];
        __syncthreads();
    }
    const float inv = 1.0f / red[0];
    __syncthreads();

    for (int j = t; j < WW; j += 256) {
        float v = (j == 0) ? 0.f : scores[b * WW + j - 1];
        weight[b * WW + j] = expf(v - m) * inv;
    }
}

__global__ void zero_x(float* __restrict__ x) {
    x[blockIdx.x * 1024 + threadIdx.x] = 0.f;
}

// K3: x[b,h] = sum_w weight[b,w] * enc[b,w,h]
template<bool FP32>
__global__ void wsum_kernel(const void* __restrict__ enc,
                            const float* __restrict__ weight,
                            const float* __restrict__ flag,
                            float* __restrict__ x) {
    if ((flag[0] < 0.5f) != FP32) return;
    __shared__ float red[16 * 128];
    const int b = blockIdx.x >> 4;
    const int chunk = blockIdx.x & 15;
    const int t = threadIdx.x;
    const int seg = t & 15;
    const int wsub = t >> 4;

    float acc[8];
#pragma unroll
    for (int j = 0; j < 8; j++) acc[j] = 0.f;

    const int wbase = chunk * 256;
#pragma unroll 4
    for (int i = 0; i < 16; i++) {
        const int w = wbase + wsub + 16 * i;
        const float wt = weight[b * WW + w];
        float v[8];
        ld8<FP32>(enc, ((size_t)(b * WW + w)) * 16 + seg, v);
#pragma unroll
        for (int j = 0; j < 8; j++) acc[j] += wt * v[j];
    }
#pragma unroll
    for (int j = 0; j < 8; j++) red[wsub * 128 + seg * 8 + j] = acc[j];
    __syncthreads();
    if (t < 128) {
        float s = 0.f;
#pragma unroll
        for (int w2 = 0; w2 < 16; w2++) s += red[w2 * 128 + t];
        atomicAdd(&x[b * HH + t], s);
    }
}

// K4: xin[b,i] = concat(x[b,:], input[b,:]) . inp_W[i,:] + inp_b[i]
template<bool FP32>
__global__ void xin_kernel(const float* __restrict__ x,
                           const void* __restrict__ input,
                           const void* __restrict__ inpW,
                           const void* __restrict__ inpb,
                           const float* __restrict__ flag,
                           float* __restrict__ xin) {
    if ((flag[0] < 0.5f) != FP32) return;
    __shared__ float xc[256];
    const int b = blockIdx.x;
    const int t = threadIdx.x;   // 128
    xc[t] = x[b * HH + t];
    xc[128 + t] = ld1<FP32>(input, b * HH + t);
    __syncthreads();
    float acc = ld1<FP32>(inpb, t);
#pragma unroll
    for (int k = 0; k < 256; k += 8) {
        float v[8];
        ld8<FP32>(inpW, ((size_t)t * 256 + k) >> 3, v);
#pragma unroll
        for (int j = 0; j < 8; j++) acc += xc[k + j] * v[j];
    }
    xin[b * HH + t] = acc;
}

// K5: one LSTM cell
template<bool FP32>
__global__ void lstm_kernel(const float* __restrict__ xv_in,
                            const void* __restrict__ hprev,
                            const void* __restrict__ cprev,
                            const void* __restrict__ W_ih,
                            const void* __restrict__ W_hh,
                            const void* __restrict__ b_ih,
                            const void* __restrict__ b_hh,
                            const float* __restrict__ flag,
                            float* __restrict__ hF_out,   // may be null
                            void* __restrict__ h_out,
                            void* __restrict__ h_out2,    // may be null
                            void* __restrict__ c_out) {
    if ((flag[0] < 0.5f) != FP32) return;
    __shared__ float xv[128];
    __shared__ float hv[128];
    __shared__ float gates[512];
    const int b = blockIdx.x;
    const int t = threadIdx.x;   // 512

    if (t < 128) {
        xv[t] = xv_in[b * HH + t];
        hv[t] = ld1<FP32>(hprev, b * HH + t);
    }
    __syncthreads();

    float acc = ld1<FP32>(b_ih, t) + ld1<FP32>(b_hh, t);
#pragma unroll
    for (int k = 0; k < 128; k += 8) {
        float v1[8], v2[8];
        ld8<FP32>(W_ih, ((size_t)t * 128 + k) >> 3, v1);
        ld8<FP32>(W_hh, ((size_t)t * 128 + k) >> 3, v2);
#pragma unroll
        for (int j = 0; j < 8; j++) acc += xv[k + j] * v1[j] + hv[k + j] * v2[j];
    }
    gates[t] = acc;
    __syncthreads();

    if (t < 128) {
        float ig = sigmoidf(gates[t]);
        float fg = sigmoidf(gates[128 + t]);
        float gg = tanhf(gates[256 + t]);
        float og = sigmoidf(gates[384 + t]);
        float cn = fg * ld1<FP32>(cprev, b * HH + t) + ig * gg;
        float hn = og * tanhf(cn);
        if (hF_out) hF_out[b * HH + t] = hn;
        st1<FP32>(h_out, b * HH + t, hn);
        if (h_out2) st1<FP32>(h_out2, b * HH + t, hn);
        st1<FP32>(c_out, b * HH + t, cn);
    }
}

// ---------------------------------------------------------------------------
extern "C" void kernel_launch(void* const* d_in, const int* in_sizes, int n_in,
                              void* d_out, int out_size, void* d_ws, size_t ws_size,
                              hipStream_t stream) {
    const void* input = d_in[0];
    const void* h0    = d_in[1];
    const void* c0    = d_in[2];
    const void* enc   = d_in[3];
    const void* attW  = d_in[4];
    const void* attb  = d_in[5];
    const void* inpW  = d_in[6];
    const void* inpb  = d_in[7];
    const void* Wih0  = d_in[8];
    const void* Whh0  = d_in[9];
    const void* bih0  = d_in[10];
    const void* bhh0  = d_in[11];
    const void* Wih1  = d_in[12];
    const void* Whh1  = d_in[13];
    const void* bih1  = d_in[14];
    const void* bhh1  = d_in[15];

    // d_out layout (elements): output(h2) [0,8192) | h1 [8192,16384) |
    //   h2 [16384,24576) | c1 [24576,32768) | c2 [32768,40960)
    char* outc = (char*)d_out;

    float* wsf    = (float*)d_ws;
    float* scores = wsf;                       // 262144
    float* weight = wsf + (size_t)BB * WW;     // 262144
    float* x      = weight + (size_t)BB * WW;  // 8192
    float* xin    = x + BB * HH;               // 8192
    float* h1f    = xin + BB * HH;             // 8192
    float* flag   = h1f + BB * HH;             // 1

    sniff_kernel<<<1, 256, 0, stream>>>((const u32*)enc, flag);

    scores_kernel<false><<<BB * WW / 256, 256, 0, stream>>>(enc, h0, c0, attW, attb, flag, scores);
    scores_kernel<true ><<<BB * WW / 256, 256, 0, stream>>>(enc, h0, c0, attW, attb, flag, scores);
    softmax_kernel<<<BB, 256, 0, stream>>>(scores, weight);
    zero_x<<<8, 1024, 0, stream>>>(x);
    wsum_kernel<false><<<BB * 16, 256, 0, stream>>>(enc, weight, flag, x);
    wsum_kernel<true ><<<BB * 16, 256, 0, stream>>>(enc, weight, flag, x);
    xin_kernel<false><<<BB, 128, 0, stream>>>(x, input, inpW, inpb, flag, xin);
    xin_kernel<true ><<<BB, 128, 0, stream>>>(x, input, inpW, inpb, flag, xin);

    // mode-specific output offsets (element size differs)
    // bf16: u16 elements; fp32: float elements
    void* o_h1_b = outc + 8192 * 2;  void* o_h1_f = outc + 8192 * 4;
    void* o_h2_b = outc + 16384 * 2; void* o_h2_f = outc + 16384 * 4;
    void* o_c1_b = outc + 24576 * 2; void* o_c1_f = outc + 24576 * 4;
    void* o_c2_b = outc + 32768 * 2; void* o_c2_f = outc + 32768 * 4;

    lstm_kernel<false><<<BB, 512, 0, stream>>>(xin, h0, c0, Wih0, Whh0, bih0, bhh0, flag,
                                               h1f, o_h1_b, (void*)nullptr, o_c1_b);
    lstm_kernel<true ><<<BB, 512, 0, stream>>>(xin, h0, c0, Wih0, Whh0, bih0, bhh0, flag,
                                               h1f, o_h1_f, (void*)nullptr, o_c1_f);

    const char* h0l1_b = (const char*)h0 + BB * HH * 2;
    const char* c0l1_b = (const char*)c0 + BB * HH * 2;
    const char* h0l1_f = (const char*)h0 + BB * HH * 4;
    const char* c0l1_f = (const char*)c0 + BB * HH * 4;

    lstm_kernel<false><<<BB, 512, 0, stream>>>(h1f, h0l1_b, c0l1_b, Wih1, Whh1, bih1, bhh1, flag,
                                               (float*)nullptr, o_h2_b, d_out, o_c2_b);
    lstm_kernel<true ><<<BB, 512, 0, stream>>>(h1f, h0l1_f, c0l1_f, Wih1, Whh1, bih1, bhh1, flag,
                                               (float*)nullptr, o_h2_f, d_out, o_c2_f);
}

// Round 3
// 285.611 us; speedup vs baseline: 1.1171x; 1.1171x over previous
//
#include <hip/hip_runtime.h>

#define BB 64
#define WW 4096
#define HH 128
#define NCHUNK 32
#define CROWS 128          // rows per chunk = WW / NCHUNK
#define PSTRIDE 132        // per-(b,chunk) partial: acc[128], m, l (+2 pad)

__device__ inline float sigmoidf(float x) { return 1.0f / (1.0f + expf(-x)); }

// ---------------------------------------------------------------------------
// K1: fused scores + online-softmax partials + unnormalized weighted enc-sum.
// grid = BB*NCHUNK blocks, 256 threads. Block (b, chunk) handles score rows
// w in [chunk*128, chunk*128+128).
//   score_w = enc[b,w,:].wa_enc + bias_b          (bias_b = att_state.wa_st + att_b)
//   softmax column j uses score_{j-1}; so p_w weights enc row w+1.
//   Row w = WW-1 is dropped by full[:, :-1] -> excluded from stats.
// Emits partials[(b*32+chunk)]: acc[128] = sum_w exp(score_w - m)*enc[b,w+1,:],
//   m = chunk max, l = chunk sum of exp.
__global__ void fused_attention(const float* __restrict__ enc,
                                const float* __restrict__ h0,
                                const float* __restrict__ c0,
                                const float* __restrict__ attW,
                                const float* __restrict__ attb,
                                float* __restrict__ partials) {
    __shared__ float s_wa[128];
    __shared__ float s_red[128];
    __shared__ float s_sc[CROWS];
    __shared__ float racc[16 * 128];
    __shared__ float s_bias, s_m, s_l;

    const int t = threadIdx.x;
    const int b = blockIdx.x >> 5;
    const int chunk = blockIdx.x & 31;
    const int w0 = chunk * CROWS;

    // --- bias_b = sum_h h0[-1]*c0[-1]*wa_st + att_b ; cache wa_enc
    if (t < 128) {
        s_wa[t] = attW[t];
        float hv = h0[BB * HH + b * HH + t];
        float cv = c0[BB * HH + b * HH + t];
        s_red[t] = hv * cv * attW[HH + t];
    }
    __syncthreads();
    for (int s = 64; s > 0; s >>= 1) {
        if (t < s) s_red[t] += s_red[t + s];
        __syncthreads();
    }
    if (t == 0) s_bias = s_red[0] + attb[0];
    __syncthreads();
    const float bias = s_bias;

    // --- scores for 128 rows: 16 lanes/row x 8 floats
    const int seg = t & 15;
    const int rg  = t >> 4;
    float wseg[8];
#pragma unroll
    for (int j = 0; j < 8; j++) wseg[j] = s_wa[seg * 8 + j];

#pragma unroll
    for (int pass = 0; pass < 8; pass++) {
        const int r = pass * 16 + rg;
        const size_t w = (size_t)w0 + r;
        const float4* p = (const float4*)(enc + ((size_t)b * WW + w) * HH + seg * 8);
        float4 a = p[0], c = p[1];
        float d = a.x * wseg[0] + a.y * wseg[1] + a.z * wseg[2] + a.w * wseg[3]
                + c.x * wseg[4] + c.y * wseg[5] + c.z * wseg[6] + c.w * wseg[7];
        d += __shfl_xor(d, 8, 16);
        d += __shfl_xor(d, 4, 16);
        d += __shfl_xor(d, 2, 16);
        d += __shfl_xor(d, 1, 16);
        if (seg == 0) s_sc[r] = (w == WW - 1) ? -1e30f : (d + bias);
    }
    __syncthreads();

    // --- chunk max m
    if (t < 64) s_red[t] = fmaxf(s_sc[t], s_sc[t + 64]);
    __syncthreads();
    for (int s = 32; s > 0; s >>= 1) {
        if (t < s) s_red[t] = fmaxf(s_red[t], s_red[t + s]);
        __syncthreads();
    }
    if (t == 0) s_m = s_red[0];
    __syncthreads();
    const float m = s_m;

    // --- p_w = exp(score - m); l = sum
    if (t < 128) s_sc[t] = expf(s_sc[t] - m);
    __syncthreads();
    if (t < 64) s_red[t] = s_sc[t] + s_sc[t + 64];
    __syncthreads();
    for (int s = 32; s > 0; s >>= 1) {
        if (t < s) s_red[t] += s_red[t + s];
        __syncthreads();
    }
    if (t == 0) s_l = s_red[0];

    // --- acc[h] = sum_w p_w * enc[b, w+1, h]   (rows mostly L2-hot)
    const int wsub = t >> 4;
    float acc8[8];
#pragma unroll
    for (int j = 0; j < 8; j++) acc8[j] = 0.f;
#pragma unroll
    for (int pass = 0; pass < 8; pass++) {
        const int r = pass * 16 + wsub;
        const size_t w = (size_t)w0 + r;
        if (w + 1 < WW) {
            const float pw = s_sc[r];
            const float4* p = (const float4*)(enc + ((size_t)b * WW + w + 1) * HH + seg * 8);
            float4 a = p[0], c = p[1];
            acc8[0] += pw * a.x; acc8[1] += pw * a.y;
            acc8[2] += pw * a.z; acc8[3] += pw * a.w;
            acc8[4] += pw * c.x; acc8[5] += pw * c.y;
            acc8[6] += pw * c.z; acc8[7] += pw * c.w;
        }
    }
#pragma unroll
    for (int j = 0; j < 8; j++) racc[wsub * 128 + seg * 8 + j] = acc8[j];
    __syncthreads();

    float* out = partials + (size_t)(b * NCHUNK + chunk) * PSTRIDE;
    if (t < 128) {
        float s = 0.f;
#pragma unroll
        for (int w2 = 0; w2 < 16; w2++) s += racc[w2 * 128 + t];
        out[t] = s;
    }
    if (t == 128) out[128] = m;
    if (t == 129) out[129] = s_l;
}

// ---------------------------------------------------------------------------
// K2: per-batch tail. Merge 32 chunk partials -> x; xin GEMV; LSTM0; LSTM1.
// grid = BB blocks, 512 threads.
__global__ void tail_kernel(const float* __restrict__ partials,
                            const float* __restrict__ enc,
                            const float* __restrict__ input,
                            const float* __restrict__ inpW,
                            const float* __restrict__ inpb,
                            const float* __restrict__ Wih0,
                            const float* __restrict__ Whh0,
                            const float* __restrict__ bih0,
                            const float* __restrict__ bhh0,
                            const float* __restrict__ Wih1,
                            const float* __restrict__ Whh1,
                            const float* __restrict__ bih1,
                            const float* __restrict__ bhh1,
                            const float* __restrict__ h0,
                            const float* __restrict__ c0,
                            float* __restrict__ out) {
    __shared__ float lm[NCHUNK], llv[NCHUNK], ls[NCHUNK];
    __shared__ float sM, sL;
    __shared__ float xc[256];       // [x | input]
    __shared__ float sxv[128];      // xin
    __shared__ float shv[128];      // h_prev
    __shared__ float sh1[128];      // h1
    __shared__ float shv2[128];     // h_prev layer 1
    __shared__ float gates[512];

    const int b = blockIdx.x;
    const int t = threadIdx.x;

    if (t < NCHUNK) {
        const float* pp = partials + (size_t)(b * NCHUNK + t) * PSTRIDE;
        lm[t] = pp[128];
        llv[t] = pp[129];
    }
    __syncthreads();
    if (t == 0) {
        float M = 0.0f;   // include the zero column in the max
        for (int c = 0; c < NCHUNK; c++) M = fmaxf(M, lm[c]);
        float L = expf(-M);   // zero column's contribution
        for (int c = 0; c < NCHUNK; c++) {
            float s = expf(lm[c] - M);
            ls[c] = s;
            L += s * llv[c];
        }
        sM = M; sL = L;
    }
    __syncthreads();

    // x[h] = (exp(-M)*enc[b,0,h] + sum_c ls[c]*acc_c[h]) / L
    if (t < 128) {
        float xv = expf(-sM) * enc[(size_t)b * WW * HH + t];
        for (int c = 0; c < NCHUNK; c++)
            xv += ls[c] * partials[(size_t)(b * NCHUNK + c) * PSTRIDE + t];
        xc[t] = xv / sL;
        xc[128 + t] = input[b * HH + t];
    }
    __syncthreads();

    // xin = inp_W . concat(x, input) + inp_b
    if (t < 128) {
        float a = inpb[t];
        const float4* wr = (const float4*)(inpW + (size_t)t * 256);
#pragma unroll
        for (int k = 0; k < 64; k++) {
            float4 w4 = wr[k];
            a += xc[4 * k] * w4.x + xc[4 * k + 1] * w4.y
               + xc[4 * k + 2] * w4.z + xc[4 * k + 3] * w4.w;
        }
        sxv[t] = a;
        shv[t] = h0[b * HH + t];
        shv2[t] = h0[BB * HH + b * HH + t];
    }
    __syncthreads();

    // ---- LSTM layer 0: 512 gate rows
    {
        float g = bih0[t] + bhh0[t];
        const float4* wi = (const float4*)(Wih0 + (size_t)t * 128);
        const float4* wh = (const float4*)(Whh0 + (size_t)t * 128);
#pragma unroll
        for (int k = 0; k < 32; k++) {
            float4 a = wi[k], c = wh[k];
            g += sxv[4 * k] * a.x + sxv[4 * k + 1] * a.y + sxv[4 * k + 2] * a.z + sxv[4 * k + 3] * a.w
               + shv[4 * k] * c.x + shv[4 * k + 1] * c.y + shv[4 * k + 2] * c.z + shv[4 * k + 3] * c.w;
        }
        gates[t] = g;
    }
    __syncthreads();
    if (t < 128) {
        float ig = sigmoidf(gates[t]);
        float fg = sigmoidf(gates[128 + t]);
        float gg = tanhf(gates[256 + t]);
        float og = sigmoidf(gates[384 + t]);
        float cn = fg * c0[b * HH + t] + ig * gg;
        float hn = og * tanhf(cn);
        out[8192 + b * HH + t] = hn;    // h-stack layer 0
        out[24576 + b * HH + t] = cn;   // c-stack layer 0
        sh1[t] = hn;
    }
    __syncthreads();

    // ---- LSTM layer 1
    {
        float g = bih1[t] + bhh1[t];
        const float4* wi = (const float4*)(Wih1 + (size_t)t * 128);
        const float4* wh = (const float4*)(Whh1 + (size_t)t * 128);
#pragma unroll
        for (int k = 0; k < 32; k++) {
            float4 a = wi[k], c = wh[k];
            g += sh1[4 * k] * a.x + sh1[4 * k + 1] * a.y + sh1[4 * k + 2] * a.z + sh1[4 * k + 3] * a.w
               + shv2[4 * k] * c.x + shv2[4 * k + 1] * c.y + shv2[4 * k + 2] * c.z + shv2[4 * k + 3] * c.w;
        }
        gates[t] = g;
    }
    __syncthreads();
    if (t < 128) {
        float ig = sigmoidf(gates[t]);
        float fg = sigmoidf(gates[128 + t]);
        float gg = tanhf(gates[256 + t]);
        float og = sigmoidf(gates[384 + t]);
        float cn = fg * c0[BB * HH + b * HH + t] + ig * gg;
        float hn = og * tanhf(cn);
        out[b * HH + t] = hn;           // output = h2
        out[16384 + b * HH + t] = hn;   // h-stack layer 1
        out[32768 + b * HH + t] = cn;   // c-stack layer 1
    }
}

// ---------------------------------------------------------------------------
extern "C" void kernel_launch(void* const* d_in, const int* in_sizes, int n_in,
                              void* d_out, int out_size, void* d_ws, size_t ws_size,
                              hipStream_t stream) {
    const float* input = (const float*)d_in[0];
    const float* h0    = (const float*)d_in[1];
    const float* c0    = (const float*)d_in[2];
    const float* enc   = (const float*)d_in[3];
    const float* attW  = (const float*)d_in[4];
    const float* attb  = (const float*)d_in[5];
    const float* inpW  = (const float*)d_in[6];
    const float* inpb  = (const float*)d_in[7];
    const float* Wih0  = (const float*)d_in[8];
    const float* Whh0  = (const float*)d_in[9];
    const float* bih0  = (const float*)d_in[10];
    const float* bhh0  = (const float*)d_in[11];
    const float* Wih1  = (const float*)d_in[12];
    const float* Whh1  = (const float*)d_in[13];
    const float* bih1  = (const float*)d_in[14];
    const float* bhh1  = (const float*)d_in[15];

    float* partials = (float*)d_ws;   // 64*32*132 floats = 1.08 MB

    fused_attention<<<BB * NCHUNK, 256, 0, stream>>>(enc, h0, c0, attW, attb, partials);
    tail_kernel<<<BB, 512, 0, stream>>>(partials, enc, input, inpW, inpb,
                                        Wih0, Whh0, bih0, bhh0,
                                        Wih1, Whh1, bih1, bhh1,
                                        h0, c0, (float*)d_out);
}

// Round 4
// 272.856 us; speedup vs baseline: 1.1694x; 1.0467x over previous
//
#include <hip/hip_runtime.h>

#define BB 64
#define WW 4096
#define HH 128
#define NCHUNK 32
#define CROWS 128          // rows per chunk = WW / NCHUNK
#define PSTRIDE 132        // per-(b,chunk) partial: acc[128], m, l (+2 pad)

__device__ inline float sigmoidf(float x) { return 1.0f / (1.0f + expf(-x)); }

// ---------------------------------------------------------------------------
// K1: fully fused single-pass attention chunk.
// Block (b, chunk) loads enc rows [w0, w0+128) into REGISTERS (64 VGPR/lane),
// computes their scores, builds the shifted weight vector
//   s_ext[r] = score(row w0+r-1)   (weights enc row w0+r)
// (one extra 512B read of row w0-1; chunk 0's r=0 weight is the softmax
// zero-column, added in the tail), takes chunk-local (m,l), and accumulates
// acc[h] = sum_r exp(s_ext[r]-m) * enc[w0+r, h] straight from registers.
// Single HBM pass over enc.
__global__ void fused_attention(const float* __restrict__ enc,
                                const float* __restrict__ h0,
                                const float* __restrict__ c0,
                                const float* __restrict__ attW,
                                const float* __restrict__ attb,
                                float* __restrict__ partials) {
    __shared__ float s_wa[128];
    __shared__ float s_red[128];
    __shared__ float s_sc[CROWS];    // raw scores of tile rows
    __shared__ float s_p[CROWS];     // shifted exp-weights
    __shared__ float racc[16 * 128];
    __shared__ float s_bias, s_m, s_extra;

    const int t = threadIdx.x;
    const int b = blockIdx.x >> 5;
    const int chunk = blockIdx.x & 31;
    const int w0 = chunk * CROWS;

    // --- bias_b = sum_h h0[-1]*c0[-1]*wa_st + att_b ; cache wa_enc
    if (t < 128) {
        s_wa[t] = attW[t];
        float hv = h0[BB * HH + b * HH + t];
        float cv = c0[BB * HH + b * HH + t];
        s_red[t] = hv * cv * attW[HH + t];
    }
    __syncthreads();
    for (int s = 64; s > 0; s >>= 1) {
        if (t < s) s_red[t] += s_red[t + s];
        __syncthreads();
    }
    if (t == 0) s_bias = s_red[0] + attb[0];
    __syncthreads();
    const float bias = s_bias;

    const int seg = t & 15;   // h-segment (8 floats)
    const int rg  = t >> 4;   // row group 0..15
    float wseg[8];
#pragma unroll
    for (int j = 0; j < 8; j++) wseg[j] = s_wa[seg * 8 + j];

    // --- load tile into registers + compute scores
    float4 ra[8], rc[8];
#pragma unroll
    for (int pass = 0; pass < 8; pass++) {
        const int r = pass * 16 + rg;
        const float4* p = (const float4*)(enc + ((size_t)b * WW + w0 + r) * HH + seg * 8);
        ra[pass] = p[0];
        rc[pass] = p[1];
        float d = ra[pass].x * wseg[0] + ra[pass].y * wseg[1]
                + ra[pass].z * wseg[2] + ra[pass].w * wseg[3]
                + rc[pass].x * wseg[4] + rc[pass].y * wseg[5]
                + rc[pass].z * wseg[6] + rc[pass].w * wseg[7];
        d += __shfl_xor(d, 8, 16);
        d += __shfl_xor(d, 4, 16);
        d += __shfl_xor(d, 2, 16);
        d += __shfl_xor(d, 1, 16);
        if (seg == 0) s_sc[r] = d + bias;
    }

    // --- extra score: row w0-1 (only chunk>0); lanes 0..15, seg==t
    if (chunk > 0 && t < 16) {
        const float4* p = (const float4*)(enc + ((size_t)b * WW + w0 - 1) * HH + t * 8);
        float4 a = p[0], c = p[1];
        float d = a.x * wseg[0] + a.y * wseg[1] + a.z * wseg[2] + a.w * wseg[3]
                + c.x * wseg[4] + c.y * wseg[5] + c.z * wseg[6] + c.w * wseg[7];
        d += __shfl_xor(d, 8, 16);
        d += __shfl_xor(d, 4, 16);
        d += __shfl_xor(d, 2, 16);
        d += __shfl_xor(d, 1, 16);
        if (t == 0) s_extra = d + bias;
    }
    __syncthreads();

    // --- shifted scores: s_p[r] = s_ext[r] = score(w0+r-1)
    if (t < 128) {
        float v;
        if (t == 0) v = (chunk > 0) ? s_extra : -1e30f;  // chunk0 r0 -> zero col (tail)
        else        v = s_sc[t - 1];
        s_p[t] = v;
    }
    __syncthreads();

    // --- chunk max m over s_p
    if (t < 64) s_red[t] = fmaxf(s_p[t], s_p[t + 64]);
    __syncthreads();
    for (int s = 32; s > 0; s >>= 1) {
        if (t < s) s_red[t] = fmaxf(s_red[t], s_red[t + s]);
        __syncthreads();
    }
    if (t == 0) s_m = s_red[0];
    __syncthreads();
    const float m = s_m;

    // --- p = exp(s_ext - m); l = sum
    if (t < 128) s_p[t] = expf(s_p[t] - m);
    __syncthreads();
    if (t < 64) s_red[t] = s_p[t] + s_p[t + 64];
    __syncthreads();
    for (int s = 32; s > 0; s >>= 1) {
        if (t < s) s_red[t] += s_red[t + s];
        __syncthreads();
    }
    // s_red[0] = l (read by t==129 below after barrier)

    // --- weighted accumulation straight from registers
    float acc8[8];
#pragma unroll
    for (int j = 0; j < 8; j++) acc8[j] = 0.f;
#pragma unroll
    for (int pass = 0; pass < 8; pass++) {
        const int r = pass * 16 + rg;
        const float pw = s_p[r];       // LDS broadcast across the 16 seg-lanes
        acc8[0] += pw * ra[pass].x; acc8[1] += pw * ra[pass].y;
        acc8[2] += pw * ra[pass].z; acc8[3] += pw * ra[pass].w;
        acc8[4] += pw * rc[pass].x; acc8[5] += pw * rc[pass].y;
        acc8[6] += pw * rc[pass].z; acc8[7] += pw * rc[pass].w;
    }
#pragma unroll
    for (int j = 0; j < 8; j++) racc[rg * 128 + seg * 8 + j] = acc8[j];
    __syncthreads();

    float* out = partials + (size_t)(b * NCHUNK + chunk) * PSTRIDE;
    if (t < 128) {
        float s = 0.f;
#pragma unroll
        for (int w2 = 0; w2 < 16; w2++) s += racc[w2 * 128 + t];
        out[t] = s;
    }
    if (t == 128) out[128] = m;
    if (t == 129) out[129] = s_red[0];
}

// ---------------------------------------------------------------------------
// K2: per-batch tail. Merge 32 chunk partials -> x; xin GEMV; LSTM0; LSTM1.
// grid = BB blocks, 512 threads.
__global__ void tail_kernel(const float* __restrict__ partials,
                            const float* __restrict__ enc,
                            const float* __restrict__ input,
                            const float* __restrict__ inpW,
                            const float* __restrict__ inpb,
                            const float* __restrict__ Wih0,
                            const float* __restrict__ Whh0,
                            const float* __restrict__ bih0,
                            const float* __restrict__ bhh0,
                            const float* __restrict__ Wih1,
                            const float* __restrict__ Whh1,
                            const float* __restrict__ bih1,
                            const float* __restrict__ bhh1,
                            const float* __restrict__ h0,
                            const float* __restrict__ c0,
                            float* __restrict__ out) {
    __shared__ float lm[NCHUNK], llv[NCHUNK], ls[NCHUNK];
    __shared__ float sM, sL;
    __shared__ float xc[256];       // [x | input]
    __shared__ float sxv[128];      // xin
    __shared__ float shv[128];      // h_prev
    __shared__ float sh1[128];      // h1
    __shared__ float shv2[128];     // h_prev layer 1
    __shared__ float gates[512];

    const int b = blockIdx.x;
    const int t = threadIdx.x;

    if (t < NCHUNK) {
        const float* pp = partials + (size_t)(b * NCHUNK + t) * PSTRIDE;
        lm[t] = pp[128];
        llv[t] = pp[129];
    }
    __syncthreads();
    if (t == 0) {
        float M = 0.0f;   // include the zero column in the max
        for (int c = 0; c < NCHUNK; c++) M = fmaxf(M, lm[c]);
        float L = expf(-M);   // zero column's contribution
        for (int c = 0; c < NCHUNK; c++) {
            float s = expf(lm[c] - M);
            ls[c] = s;
            L += s * llv[c];
        }
        sM = M; sL = L;
    }
    __syncthreads();

    // x[h] = (exp(-M)*enc[b,0,h] + sum_c ls[c]*acc_c[h]) / L
    if (t < 128) {
        float xv = expf(-sM) * enc[(size_t)b * WW * HH + t];
        for (int c = 0; c < NCHUNK; c++)
            xv += ls[c] * partials[(size_t)(b * NCHUNK + c) * PSTRIDE + t];
        xc[t] = xv / sL;
        xc[128 + t] = input[b * HH + t];
    }
    __syncthreads();

    // xin = inp_W . concat(x, input) + inp_b
    if (t < 128) {
        float a = inpb[t];
        const float4* wr = (const float4*)(inpW + (size_t)t * 256);
#pragma unroll
        for (int k = 0; k < 64; k++) {
            float4 w4 = wr[k];
            a += xc[4 * k] * w4.x + xc[4 * k + 1] * w4.y
               + xc[4 * k + 2] * w4.z + xc[4 * k + 3] * w4.w;
        }
        sxv[t] = a;
        shv[t] = h0[b * HH + t];
        shv2[t] = h0[BB * HH + b * HH + t];
    }
    __syncthreads();

    // ---- LSTM layer 0: 512 gate rows
    {
        float g = bih0[t] + bhh0[t];
        const float4* wi = (const float4*)(Wih0 + (size_t)t * 128);
        const float4* wh = (const float4*)(Whh0 + (size_t)t * 128);
#pragma unroll
        for (int k = 0; k < 32; k++) {
            float4 a = wi[k], c = wh[k];
            g += sxv[4 * k] * a.x + sxv[4 * k + 1] * a.y + sxv[4 * k + 2] * a.z + sxv[4 * k + 3] * a.w
               + shv[4 * k] * c.x + shv[4 * k + 1] * c.y + shv[4 * k + 2] * c.z + shv[4 * k + 3] * c.w;
        }
        gates[t] = g;
    }
    __syncthreads();
    if (t < 128) {
        float ig = sigmoidf(gates[t]);
        float fg = sigmoidf(gates[128 + t]);
        float gg = tanhf(gates[256 + t]);
        float og = sigmoidf(gates[384 + t]);
        float cn = fg * c0[b * HH + t] + ig * gg;
        float hn = og * tanhf(cn);
        out[8192 + b * HH + t] = hn;    // h-stack layer 0
        out[24576 + b * HH + t] = cn;   // c-stack layer 0
        sh1[t] = hn;
    }
    __syncthreads();

    // ---- LSTM layer 1
    {
        float g = bih1[t] + bhh1[t];
        const float4* wi = (const float4*)(Wih1 + (size_t)t * 128);
        const float4* wh = (const float4*)(Whh1 + (size_t)t * 128);
#pragma unroll
        for (int k = 0; k < 32; k++) {
            float4 a = wi[k], c = wh[k];
            g += sh1[4 * k] * a.x + sh1[4 * k + 1] * a.y + sh1[4 * k + 2] * a.z + sh1[4 * k + 3] * a.w
               + shv2[4 * k] * c.x + shv2[4 * k + 1] * c.y + shv2[4 * k + 2] * c.z + shv2[4 * k + 3] * c.w;
        }
        gates[t] = g;
    }
    __syncthreads();
    if (t < 128) {
        float ig = sigmoidf(gates[t]);
        float fg = sigmoidf(gates[128 + t]);
        float gg = tanhf(gates[256 + t]);
        float og = sigmoidf(gates[384 + t]);
        float cn = fg * c0[BB * HH + b * HH + t] + ig * gg;
        float hn = og * tanhf(cn);
        out[b * HH + t] = hn;           // output = h2
        out[16384 + b * HH + t] = hn;   // h-stack layer 1
        out[32768 + b * HH + t] = cn;   // c-stack layer 1
    }
}

// ---------------------------------------------------------------------------
extern "C" void kernel_launch(void* const* d_in, const int* in_sizes, int n_in,
                              void* d_out, int out_size, void* d_ws, size_t ws_size,
                              hipStream_t stream) {
    const float* input = (const float*)d_in[0];
    const float* h0    = (const float*)d_in[1];
    const float* c0    = (const float*)d_in[2];
    const float* enc   = (const float*)d_in[3];
    const float* attW  = (const float*)d_in[4];
    const float* attb  = (const float*)d_in[5];
    const float* inpW  = (const float*)d_in[6];
    const float* inpb  = (const float*)d_in[7];
    const float* Wih0  = (const float*)d_in[8];
    const float* Whh0  = (const float*)d_in[9];
    const float* bih0  = (const float*)d_in[10];
    const float* bhh0  = (const float*)d_in[11];
    const float* Wih1  = (const float*)d_in[12];
    const float* Whh1  = (const float*)d_in[13];
    const float* bih1  = (const float*)d_in[14];
    const float* bhh1  = (const float*)d_in[15];

    float* partials = (float*)d_ws;   // 64*32*132 floats = 1.08 MB

    fused_attention<<<BB * NCHUNK, 256, 0, stream>>>(enc, h0, c0, attW, attb, partials);
    tail_kernel<<<BB, 512, 0, stream>>>(partials, enc, input, inpW, inpb,
                                        Wih0, Whh0, bih0, bhh0,
                                        Wih1, Whh1, bih1, bhh1,
                                        h0, c0, (float*)d_out);
}